// Round 4
// baseline (149.979 us; speedup 1.0000x reference)
//
#include <hip/hip_runtime.h>
#include <stdint.h>

// Sparse top-k attention, B=1 S=2048 H=16 D=128 N_KV=8192 K=512.
// R4: 16-key tiles x 8 (half the LDS -> ~6 blocks/CU instead of 3; occupancy
// is the bottleneck per R3 counters: all pipes <30% busy). PV via
// mfma_f32_16x16x16bf16_1k (k=16). Raw v_exp_f32 for softmax. Single-buffered
// gather; latency hidden by waves, not prefetch. Zero barriers in key loop.

typedef float  f32x4 __attribute__((ext_vector_type(4)));
typedef short  s16x8 __attribute__((ext_vector_type(8)));
typedef short  s16x4 __attribute__((ext_vector_type(4)));

#define S_LEN   2048
#define N_HEADS 16
#define D_HEAD  128
#define TOPK    512

// LDS map (bytes):
//  [0,17536)       V tiles: wave w at w*4384; row r (0..15) at KVROW(r),
//                  256B bf16 data per row (skew: conflict-free column reads)
//                  (epilogue reuse: OA [16][132] f32 at 0, OB at 8448)
//  [17536,20096)   P tiles: wave w at +w*640; row h: 20 ushorts (16 used)
//  [20096,20352)   lsum [4][16] f32
#define KV_WAVE   4384
#define P_BASE    17536
#define P_WAVE    640
#define LSUM_BASE 20096
#define SMEM_BYTES 20352
#define KVROW(r) ((((r) >> 3) * 2208) + (((r) & 7) * 272))

// fp32 -> bf16 round-nearest-even
__device__ __forceinline__ unsigned short f2bf(float f) {
  union { float f; unsigned u; } v; v.f = f;
  return (unsigned short)((v.u + 0x7fffu + ((v.u >> 16) & 1u)) >> 16);
}

__global__ void __launch_bounds__(256) kv_cvt_bf16(
    const float* __restrict__ kv, unsigned short* __restrict__ o) {
  int i = (blockIdx.x * 256 + threadIdx.x) * 8;   // 8192*128 = 1M elems, grid 512
  float4 a = *(const float4*)(kv + i);
  float4 b = *(const float4*)(kv + i + 4);
  uint4 p;
  p.x = (unsigned)f2bf(a.x) | ((unsigned)f2bf(a.y) << 16);
  p.y = (unsigned)f2bf(a.z) | ((unsigned)f2bf(a.w) << 16);
  p.z = (unsigned)f2bf(b.x) | ((unsigned)f2bf(b.y) << 16);
  p.w = (unsigned)f2bf(b.z) | ((unsigned)f2bf(b.w) << 16);
  *(uint4*)(o + i) = p;
}

__global__ void __launch_bounds__(256, 6) g2core_sparse_attn(
    const float* __restrict__ qg, const unsigned short* __restrict__ kvb,
    const int* __restrict__ tkg, float* __restrict__ outg) {
  __shared__ __align__(16) char smem[SMEM_BYTES];
  unsigned short* p_all = (unsigned short*)(smem + P_BASE);
  float*          lsum  = (float*)(smem + LSUM_BASE);

  const int s    = blockIdx.x;
  const int tid  = threadIdx.x;
  const int wave = __builtin_amdgcn_readfirstlane(tid >> 6);
  const int lane = tid & 63;
  const int quad = lane >> 4;   // 0..3
  const int n16  = lane & 15;   // 0..15

  char*           kvw_b = smem + wave * KV_WAVE;
  unsigned short* pw    = p_all + wave * (P_WAVE / 2);

  // fold 1/sqrt(128) * log2(e) into Q; softmax runs unnormalized in exp2 domain
  const float QSCALE = 0.08838834764831845f * 1.4426950408889634f;

  // ---- Q A-frags (16x16x32): A[m=n16(head)][k=32c+8*quad+j] ----
  s16x8 qf[4];
  {
    const float* qrow = qg + ((size_t)s * N_HEADS + n16) * D_HEAD;
#pragma unroll
    for (int c = 0; c < 4; ++c) {
      const float* p0 = qrow + c * 32 + quad * 8;
      float4 a = *(const float4*)(p0);
      float4 b = *(const float4*)(p0 + 4);
      s16x8 f;
      f[0] = (short)f2bf(a.x * QSCALE); f[1] = (short)f2bf(a.y * QSCALE);
      f[2] = (short)f2bf(a.z * QSCALE); f[3] = (short)f2bf(a.w * QSCALE);
      f[4] = (short)f2bf(b.x * QSCALE); f[5] = (short)f2bf(b.y * QSCALE);
      f[6] = (short)f2bf(b.z * QSCALE); f[7] = (short)f2bf(b.w * QSCALE);
      qf[c] = f;
    }
  }

  // ones-column B-frag (16x16x16): B[k][0]=1 else 0
  s16x4 ones_f;
#pragma unroll
  for (int j = 0; j < 4; ++j) ones_f[j] = (n16 == 0) ? (short)0x3F80 : (short)0;

  f32x4 o_acc[8];
  f32x4 o_l = (f32x4){0.f, 0.f, 0.f, 0.f};
#pragma unroll
  for (int t = 0; t < 8; ++t) o_acc[t] = (f32x4){0.f, 0.f, 0.f, 0.f};

  const int* tk = tkg + (size_t)s * TOPK + wave * 128;
  const unsigned short* kvw16 = (const unsigned short*)kvw_b;

  // ================= key loop: 8 tiles x 16 keys, wave-private =================
#pragma unroll 2
  for (int t = 0; t < 8; ++t) {
    int ki0 = tk[t * 16 + n16];            // this lane's key (key index = n16)
    int ki  = ki0 < 0 ? 0 : ki0;

    // ---- gather: row ki, 4x dwordx4 (64B per c-chunk, quads contiguous) ----
    const char* rp = (const char*)kvb + (size_t)ki * 256 + quad * 16;
    s16x8 kst[4];
#pragma unroll
    for (int c = 0; c < 4; ++c) kst[c] = *(const s16x8*)(rp + c * 64);

    // ---- stage V rows into skewed LDS (4 ds_write_b128) ----
    char* wrow = kvw_b + KVROW(n16) + quad * 16;
#pragma unroll
    for (int c = 0; c < 4; ++c) *(s16x8*)(wrow + c * 64) = kst[c];

    // ---- QK (16x16x32 over d): S[h=quad*4+r][key=n16] ----
    f32x4 sa = (f32x4){0.f, 0.f, 0.f, 0.f};
#pragma unroll
    for (int c = 0; c < 4; ++c)
      sa = __builtin_amdgcn_mfma_f32_16x16x32_bf16(qf[c], kst[c], sa, 0, 0, 0);
    float bias = (ki0 < 0) ? -30000.0f : 0.0f;
#pragma unroll
    for (int r = 0; r < 4; ++r)
      pw[(quad * 4 + r) * 20 + n16] = f2bf(__builtin_amdgcn_exp2f(sa[r] + bias));

    // ---- PV (16x16x16, k=16 keys): A=P from LDS, B=V columns (conflict-free) ----
    s16x4 pf = *(const s16x4*)(pw + n16 * 20 + quad * 4);
#pragma unroll
    for (int dt = 0; dt < 8; ++dt) {
      s16x4 vf;
#pragma unroll
      for (int j = 0; j < 4; ++j)
        vf[j] = (short)kvw16[(KVROW(quad * 4 + j) >> 1) + dt * 16 + n16];
      o_acc[dt] = __builtin_amdgcn_mfma_f32_16x16x16bf16_1k(pf, vf, o_acc[dt], 0, 0, 0);
    }
    o_l = __builtin_amdgcn_mfma_f32_16x16x16bf16_1k(pf, ones_f, o_l, 0, 0, 0);
  }

  // ================= cross-wave combine: two-round LDS reduce =================
  __syncthreads();                       // all waves done with V/P reads
  float* OA = (float*)smem;              // [16][132] f32
  float* OB = (float*)(smem + 8448);
  float* dst = (wave & 1) ? OB : OA;
  if (wave < 2) {
#pragma unroll
    for (int dt = 0; dt < 8; ++dt)
#pragma unroll
      for (int r = 0; r < 4; ++r)
        dst[(quad * 4 + r) * 132 + dt * 16 + n16] = o_acc[dt][r];
  }
  if (n16 == 0) {
#pragma unroll
    for (int r = 0; r < 4; ++r) lsum[wave * 16 + quad * 4 + r] = o_l[r];
  }
  __syncthreads();
  if (wave >= 2) {
#pragma unroll
    for (int dt = 0; dt < 8; ++dt)
#pragma unroll
      for (int r = 0; r < 4; ++r) {
        int idx = (quad * 4 + r) * 132 + dt * 16 + n16;
        dst[idx] += o_acc[dt][r];
      }
  }
  __syncthreads();

  float* outp = outg + (size_t)s * (N_HEADS * D_HEAD);
#pragma unroll
  for (int i = 0; i < 8; ++i) {
    int e = i * 256 + tid;               // 0..2047
    int h = e >> 7, d = e & 127;
    float ls = lsum[h] + lsum[16 + h] + lsum[32 + h] + lsum[48 + h];
    outp[e] = (OA[h * 132 + d] + OB[h * 132 + d]) / ls;
  }
}

extern "C" void kernel_launch(void* const* d_in, const int* in_sizes, int n_in,
                              void* d_out, int out_size, void* d_ws, size_t ws_size,
                              hipStream_t stream) {
  const float* q    = (const float*)d_in[0];
  const float* kv   = (const float*)d_in[1];
  const int*   topk = (const int*)d_in[2];
  float*       out  = (float*)d_out;
  unsigned short* kvb = (unsigned short*)d_ws;   // 8192*128*2 = 2 MB scratch

  kv_cvt_bf16<<<dim3(512), dim3(256), 0, stream>>>(kv, kvb);
  g2core_sparse_attn<<<dim3(S_LEN), dim3(256), 0, stream>>>(q, kvb, topk, out);
}

// Round 5
// 116.376 us; speedup vs baseline: 1.2887x; 1.2887x over previous
//
#include <hip/hip_runtime.h>
#include <stdint.h>

// Sparse top-k attention, B=1 S=2048 H=16 D=128 N_KV=8192 K=512.
// R5: R4 structure (16-key tiles x 8, ~20 KB LDS) with the register budget
// fixed: __launch_bounds__(256,5) -> ~102-reg cap, no scratch spills (R4's
// (256,6) forced an ~85-reg cap -> ~43 regs spilled -> +140 MB HBM traffic).
// PV via mfma_f32_16x16x16bf16_1k; raw v_exp_f32 softmax; no-max softmax with
// l from a ones-column MFMA. Zero barriers in the key loop.

typedef float  f32x4 __attribute__((ext_vector_type(4)));
typedef short  s16x8 __attribute__((ext_vector_type(8)));
typedef short  s16x4 __attribute__((ext_vector_type(4)));

#define S_LEN   2048
#define N_HEADS 16
#define D_HEAD  128
#define TOPK    512

// LDS map (bytes):
//  [0,17536)       V tiles: wave w at w*4384; row r (0..15) at KVROW(r),
//                  256B bf16 data per row (skew: conflict-free column reads)
//                  (epilogue reuse: OA [16][132] f32 at 0, OB at 8448)
//  [17536,20096)   P tiles: wave w at +w*640; row h: 20 ushorts (16 used)
//  [20096,20352)   lsum [4][16] f32
#define KV_WAVE   4384
#define P_BASE    17536
#define P_WAVE    640
#define LSUM_BASE 20096
#define SMEM_BYTES 20352
#define KVROW(r) ((((r) >> 3) * 2208) + (((r) & 7) * 272))

// fp32 -> bf16 round-nearest-even
__device__ __forceinline__ unsigned short f2bf(float f) {
  union { float f; unsigned u; } v; v.f = f;
  return (unsigned short)((v.u + 0x7fffu + ((v.u >> 16) & 1u)) >> 16);
}

__global__ void __launch_bounds__(256) kv_cvt_bf16(
    const float* __restrict__ kv, unsigned short* __restrict__ o) {
  int i = (blockIdx.x * 256 + threadIdx.x) * 8;   // 8192*128 = 1M elems, grid 512
  float4 a = *(const float4*)(kv + i);
  float4 b = *(const float4*)(kv + i + 4);
  uint4 p;
  p.x = (unsigned)f2bf(a.x) | ((unsigned)f2bf(a.y) << 16);
  p.y = (unsigned)f2bf(a.z) | ((unsigned)f2bf(a.w) << 16);
  p.z = (unsigned)f2bf(b.x) | ((unsigned)f2bf(b.y) << 16);
  p.w = (unsigned)f2bf(b.z) | ((unsigned)f2bf(b.w) << 16);
  *(uint4*)(o + i) = p;
}

__global__ void __launch_bounds__(256, 5) g2core_sparse_attn(
    const float* __restrict__ qg, const unsigned short* __restrict__ kvb,
    const int* __restrict__ tkg, float* __restrict__ outg) {
  __shared__ __align__(16) char smem[SMEM_BYTES];
  unsigned short* p_all = (unsigned short*)(smem + P_BASE);
  float*          lsum  = (float*)(smem + LSUM_BASE);

  const int s    = blockIdx.x;
  const int tid  = threadIdx.x;
  const int wave = __builtin_amdgcn_readfirstlane(tid >> 6);
  const int lane = tid & 63;
  const int quad = lane >> 4;   // 0..3
  const int n16  = lane & 15;   // 0..15

  char*           kvw_b = smem + wave * KV_WAVE;
  unsigned short* pw    = p_all + wave * (P_WAVE / 2);

  // fold 1/sqrt(128) * log2(e) into Q; softmax runs unnormalized in exp2 domain
  const float QSCALE = 0.08838834764831845f * 1.4426950408889634f;

  // ---- Q A-frags (16x16x32): A[m=n16(head)][k=32c+8*quad+j] ----
  s16x8 qf[4];
  {
    const float* qrow = qg + ((size_t)s * N_HEADS + n16) * D_HEAD;
#pragma unroll
    for (int c = 0; c < 4; ++c) {
      const float* p0 = qrow + c * 32 + quad * 8;
      float4 a = *(const float4*)(p0);
      float4 b = *(const float4*)(p0 + 4);
      s16x8 f;
      f[0] = (short)f2bf(a.x * QSCALE); f[1] = (short)f2bf(a.y * QSCALE);
      f[2] = (short)f2bf(a.z * QSCALE); f[3] = (short)f2bf(a.w * QSCALE);
      f[4] = (short)f2bf(b.x * QSCALE); f[5] = (short)f2bf(b.y * QSCALE);
      f[6] = (short)f2bf(b.z * QSCALE); f[7] = (short)f2bf(b.w * QSCALE);
      qf[c] = f;
    }
  }

  // ones-column B-frag (16x16x16): B[k][0]=1 else 0
  s16x4 ones_f;
#pragma unroll
  for (int j = 0; j < 4; ++j) ones_f[j] = (n16 == 0) ? (short)0x3F80 : (short)0;

  f32x4 o_acc[8];
  f32x4 o_l = (f32x4){0.f, 0.f, 0.f, 0.f};
#pragma unroll
  for (int t = 0; t < 8; ++t) o_acc[t] = (f32x4){0.f, 0.f, 0.f, 0.f};

  const int* tk = tkg + (size_t)s * TOPK + wave * 128;
  const unsigned short* kvw16 = (const unsigned short*)kvw_b;

  // ================= key loop: 8 tiles x 16 keys, wave-private =================
#pragma unroll 2
  for (int t = 0; t < 8; ++t) {
    int ki0 = tk[t * 16 + n16];            // this lane's key (key index = n16)
    int ki  = ki0 < 0 ? 0 : ki0;

    // ---- gather: row ki, 4x dwordx4 (full 256B row covered by the 4 quads) ----
    const char* rp = (const char*)kvb + (size_t)ki * 256 + quad * 16;
    s16x8 kst[4];
#pragma unroll
    for (int c = 0; c < 4; ++c) kst[c] = *(const s16x8*)(rp + c * 64);

    // ---- stage V rows into skewed LDS (4 ds_write_b128) ----
    char* wrow = kvw_b + KVROW(n16) + quad * 16;
#pragma unroll
    for (int c = 0; c < 4; ++c) *(s16x8*)(wrow + c * 64) = kst[c];

    // ---- QK (16x16x32 over d): S[h=quad*4+r][key=n16] ----
    f32x4 sa = (f32x4){0.f, 0.f, 0.f, 0.f};
#pragma unroll
    for (int c = 0; c < 4; ++c)
      sa = __builtin_amdgcn_mfma_f32_16x16x32_bf16(qf[c], kst[c], sa, 0, 0, 0);
    float bias = (ki0 < 0) ? -30000.0f : 0.0f;
#pragma unroll
    for (int r = 0; r < 4; ++r)
      pw[(quad * 4 + r) * 20 + n16] = f2bf(__builtin_amdgcn_exp2f(sa[r] + bias));

    // ---- PV (16x16x16, k=16 keys): A=P from LDS, B=V columns (conflict-free) ----
    s16x4 pf = *(const s16x4*)(pw + n16 * 20 + quad * 4);
#pragma unroll
    for (int dt = 0; dt < 8; ++dt) {
      s16x4 vf;
#pragma unroll
      for (int j = 0; j < 4; ++j)
        vf[j] = (short)kvw16[(KVROW(quad * 4 + j) >> 1) + dt * 16 + n16];
      o_acc[dt] = __builtin_amdgcn_mfma_f32_16x16x16bf16_1k(pf, vf, o_acc[dt], 0, 0, 0);
    }
    o_l = __builtin_amdgcn_mfma_f32_16x16x16bf16_1k(pf, ones_f, o_l, 0, 0, 0);
  }

  // ================= cross-wave combine: two-round LDS reduce =================
  __syncthreads();                       // all waves done with V/P reads
  float* OA = (float*)smem;              // [16][132] f32
  float* OB = (float*)(smem + 8448);
  float* dst = (wave & 1) ? OB : OA;
  if (wave < 2) {
#pragma unroll
    for (int dt = 0; dt < 8; ++dt)
#pragma unroll
      for (int r = 0; r < 4; ++r)
        dst[(quad * 4 + r) * 132 + dt * 16 + n16] = o_acc[dt][r];
  }
  if (n16 == 0) {
#pragma unroll
    for (int r = 0; r < 4; ++r) lsum[wave * 16 + quad * 4 + r] = o_l[r];
  }
  __syncthreads();
  if (wave >= 2) {
#pragma unroll
    for (int dt = 0; dt < 8; ++dt)
#pragma unroll
      for (int r = 0; r < 4; ++r) {
        int idx = (quad * 4 + r) * 132 + dt * 16 + n16;
        dst[idx] += o_acc[dt][r];
      }
  }
  __syncthreads();

  float* outp = outg + (size_t)s * (N_HEADS * D_HEAD);
#pragma unroll
  for (int i = 0; i < 8; ++i) {
    int e = i * 256 + tid;               // 0..2047
    int h = e >> 7, d = e & 127;
    float ls = lsum[h] + lsum[16 + h] + lsum[32 + h] + lsum[48 + h];
    outp[e] = (OA[h * 132 + d] + OB[h * 132 + d]) / ls;
  }
}

extern "C" void kernel_launch(void* const* d_in, const int* in_sizes, int n_in,
                              void* d_out, int out_size, void* d_ws, size_t ws_size,
                              hipStream_t stream) {
  const float* q    = (const float*)d_in[0];
  const float* kv   = (const float*)d_in[1];
  const int*   topk = (const int*)d_in[2];
  float*       out  = (float*)d_out;
  unsigned short* kvb = (unsigned short*)d_ws;   // 8192*128*2 = 2 MB scratch

  kv_cvt_bf16<<<dim3(512), dim3(256), 0, stream>>>(kv, kvb);
  g2core_sparse_attn<<<dim3(S_LEN), dim3(256), 0, stream>>>(q, kvb, topk, out);
}